// Round 12
// baseline (112.943 us; speedup 1.0000x reference)
//
#include <hip/hip_runtime.h>
#include <hip/hip_bf16.h>

#define BB   16
#define CIN  256
#define COUT 256
#define WD   256
#define HH   64
#define WWS  64
#define NSP  4096      // HH*WWS
#define KW   9

typedef __attribute__((ext_vector_type(8))) short short8;
typedef __attribute__((ext_vector_type(4))) float f32x4;
typedef unsigned short ushort_t;
typedef unsigned int uint_t;

// workspace layout
#define S_BYTES (BB*CIN*4)                       // 16 KB
#define WT_OFF (S_BYTES)
#define WT_BYTES (BB*9*COUT*CIN*2)               // 18.87 MB
#define X_OFF (WT_OFF + WT_BYTES)
#define X_BYTES (BB*NSP*CIN*2)                   // 33.55 MB
#define ZP_OFF (X_OFF + X_BYTES)
#define ZP_BYTES 4096
#define WS_NEEDED ((size_t)(ZP_OFF + ZP_BYTES))

#define WAITVM0 asm volatile("s_waitcnt vmcnt(0)" ::: "memory")
#define WAITVM4 asm volatile("s_waitcnt vmcnt(4)" ::: "memory")

__device__ inline ushort_t f2bf(float f) {
    __hip_bfloat16 h = __float2bfloat16(f);
    return __builtin_bit_cast(ushort_t, h);
}

__device__ inline void gload_lds16(const ushort_t* g, ushort_t* l) {
    __builtin_amdgcn_global_load_lds(
        (const __attribute__((address_space(1))) void*)g,
        (__attribute__((address_space(3))) void*)l, 16, 0, 0);
}

// ---------------------------------------------------------------------------
// Kernel 1: style modulation
// ---------------------------------------------------------------------------
__global__ __launch_bounds__(256)
void style_kernel(const float* __restrict__ w,
                  const float* __restrict__ style_w,
                  const float* __restrict__ style_b,
                  float* __restrict__ s) {
    const int b  = blockIdx.x;
    const int ci = threadIdx.x;
    __shared__ float wsh[WD];
    wsh[ci] = w[b * WD + ci];
    __syncthreads();
    const float* row = style_w + ci * WD;
    float acc = style_b[ci];
    #pragma unroll 4
    for (int k = 0; k < WD; ++k) acc += wsh[k] * row[k];
    s[b * CIN + ci] = acc;
}

// ---------------------------------------------------------------------------
// Kernel 2: demodulated weights -> bf16, layout [b][tap][co][ci]
//           (block (0,0) also zero-fills the zp page used by conv)
// ---------------------------------------------------------------------------
__global__ __launch_bounds__(256)
void wt_kernel(const float* __restrict__ cw, const float* __restrict__ s,
               const float* __restrict__ scale_p, ushort_t* __restrict__ wt,
               float* __restrict__ zp) {
    const int co = blockIdx.x, b = blockIdx.y, ci = threadIdx.x;
    if (co == 0 && b == 0)
        ((float4*)zp)[ci] = make_float4(0.f, 0.f, 0.f, 0.f);
    const float sv = s[b * CIN + ci] * scale_p[0];
    const float* cp = cw + ((size_t)co * CIN + ci) * KW;
    float v[9];
    float ss = 0.f;
    #pragma unroll
    for (int t = 0; t < 9; ++t) { v[t] = cp[t] * sv; ss += v[t] * v[t]; }
    #pragma unroll
    for (int off = 32; off > 0; off >>= 1) ss += __shfl_down(ss, off);
    __shared__ float red[4];
    if ((ci & 63) == 0) red[ci >> 6] = ss;
    __syncthreads();
    const float dm = rsqrtf(red[0] + red[1] + red[2] + red[3] + 1e-8f);
    #pragma unroll
    for (int t = 0; t < 9; ++t)
        wt[((size_t)(b * 9 + t) * COUT + co) * CIN + ci] = f2bf(v[t] * dm);
}

// ---------------------------------------------------------------------------
// Kernel 3: x NCHW fp32 -> NHWC bf16  (xo[b][sp][ci]); uint4 stores
// ---------------------------------------------------------------------------
__global__ __launch_bounds__(256)
void xpose_kernel(const float* __restrict__ x, ushort_t* __restrict__ xo) {
    const int spt = blockIdx.x;
    const int cit = blockIdx.y;
    const int b   = blockIdx.z;
    const int t   = threadIdx.x;
    __shared__ ushort_t tile[64 * 72];
    const int sp0 = spt * 64, ci0 = cit * 64;
    {
        const int spq = t & 15, cil = t >> 4;
        #pragma unroll
        for (int i = 0; i < 4; ++i) {
            const int ci = cil + i * 16;
            const float4 v = *(const float4*)(x + ((size_t)(b * CIN + ci0 + ci)) * NSP + sp0 + spq * 4);
            tile[(spq * 4 + 0) * 72 + ci] = f2bf(v.x);
            tile[(spq * 4 + 1) * 72 + ci] = f2bf(v.y);
            tile[(spq * 4 + 2) * 72 + ci] = f2bf(v.z);
            tile[(spq * 4 + 3) * 72 + ci] = f2bf(v.w);
        }
    }
    __syncthreads();
    {
        const int g8 = t & 7, sp = t >> 3;     // sp 0..31
        #pragma unroll
        for (int i = 0; i < 2; ++i) {
            const int spp = sp + i * 32;
            uint4 v = *(const uint4*)&tile[spp * 72 + g8 * 8];
            *(uint4*)(xo + ((size_t)(b * NSP + sp0 + spp)) * CIN + ci0 + g8 * 8) = v;
        }
    }
}

// ---------------------------------------------------------------------------
// Kernel 4: implicit-GEMM conv, 1 wave/SIMD + intra-wave pipelining.
//   256 blocks (16 b x 16 ntile, 1/CU), 256 threads = 4 waves (2M x 2N).
//   Block tile 256co x 256sp; wave tile 128x128 -> acc[8][8] (256 VGPR).
//   Per tap u: [issue A(u+2) DMA] [vmcnt(4) counted] [s_barrier]
//              [prefetch frags(u+1) -> reg set Q] [64 MFMA on set P].
//   The prefetch lgkm latency hides fully under the ~1242-cyc MFMA burst;
//   wait-BEFORE-barrier publishes all waves' A(u+1) DMA writes (per-wave
//   vmcnt covers only own writes -- barrier after wait fixes visibility).
//   A: [3][256co][32ci] triple-buffer via global_load_lds (4 calls/thr/tap,
//      2 taps ahead). x: resident ci-quarter [6][66][64] (0-conflict layout,
//      R10-verified), restaged 4x at quarter boundaries.
//   LDS 99840 B -> 1 block/CU (deliberate; ILP replaces TLP).
// ---------------------------------------------------------------------------
__global__ __launch_bounds__(256, 1)
void conv_mfma_kernel(const ushort_t* __restrict__ wt,   // [b][9][256][256]
                      const ushort_t* __restrict__ xo,   // [b][4096][256]
                      const ushort_t* __restrict__ zp,   // zero page
                      float* __restrict__ out) {
    const int wg    = blockIdx.x;              // 0..255
    const int b     = (wg & 7) | (((wg >> 3) & 1) << 3);  // batch per XCD
    const int ntile = wg >> 4;                 // 0..15
    const int y0    = ntile * 4;

    const int tid  = threadIdx.x;
    const int lane = tid & 63;
    const int w    = tid >> 6;                 // wave 0..3
    const int wm   = w >> 1;                   // co 128-half
    const int wn   = w & 1;                    // spatial 128-half
    const int wn2  = wn * 2;
    const int l15  = lane & 15;
    const int lg   = lane >> 4;

    __shared__ __align__(16) ushort_t lds_x[6 * 66 * 64];    // 50688 B
    __shared__ __align__(16) ushort_t lds_a[3 * 256 * 32];   // 49152 B

    // ---- A DMA (per thread): call i covers co row i*64 + (tid>>2) ----
    const int srcqA = ((tid & 3) ^ ((tid >> 2) & 3)) * 8;    // involution
    const ushort_t* paDMA = wt + (size_t)b * (9 * COUT * CIN)
                          + (uint_t)(tid >> 2) * CIN + srcqA;
    const ushort_t* xob = xo + (size_t)b * (NSP * CIN);

    // ---- af read base: row = wm*128 + mi*16 + l15, slot = lg ^ (row&3) ----
    const int sA8   = (lg ^ (l15 & 3)) * 8;
    const int abase = (wm * 128 + l15) * 32 + sA8;

    // ---- bf read bases (R11-verified): bx[chunkpar][kx] ----
    int bx[2][3];
    #pragma unroll
    for (int c4 = 0; c4 < 2; ++c4)
        #pragma unroll
        for (int kx = 0; kx < 3; ++kx) {
            const int k7 = (l15 + kx) & 7;
            bx[c4][kx] = (wn2 * 66 + l15 + kx) * 64 + ((c4 * 4 + lg) ^ k7) * 8;
        }

    f32x4 acc[8][8];
    #pragma unroll
    for (int mi = 0; mi < 8; ++mi)
        #pragma unroll
        for (int ni = 0; ni < 8; ++ni) acc[mi][ni] = (f32x4){0.f, 0.f, 0.f, 0.f};

    short8 afr[2][8], bfr[2][8];

    // ---- zero halo cols (0 and 65), rows 0..5, once ----
    if (tid < 96) {
        const int cell = tid >> 3;             // 0..11
        const int r = cell >> 1, c = (cell & 1) * 65;
        *(uint4*)&lds_x[(r * 66 + c) * 64 + (tid & 7) * 8] =
            make_uint4(0, 0, 0, 0);
    }

    // ---- x staging (R10-verbatim): 12 calls/thread, 48 regions ----
    #define STAGE_X(qt)                                                        \
    {   _Pragma("unroll")                                                      \
        for (int i_ = 0; i_ < 12; ++i_) {                                      \
            const int cell_ = i_ * 4 + w;      /* 0..47 */                     \
            const int r_  = cell_ >> 3;        /* 0..5 */                      \
            const int c0_ = 1 + (cell_ & 7) * 8;                               \
            const int y_  = y0 - 1 + r_;                                       \
            const int c_  = c0_ + (lane >> 3);                                 \
            const int qq_ = (lane & 7) ^ (c_ & 7);                             \
            const ushort_t* src_ = (y_ >= 0 && y_ < HH)                        \
                ? (xob + (uint_t)(y_ * WWS + c_ - 1) * CIN + (qt) * 64         \
                       + qq_ * 8)                                              \
                : (zp + lane * 8);                                             \
            gload_lds16(src_, lds_x + (r_ * 66 + c0_) * 64 + lane * 8);        \
        }                                                                      \
    }

    #define ISSUE_A(tp, cg, buf)                                               \
    {   const ushort_t* as_ = paDMA + (tp) * 65536 + (cg) * 32;                \
        ushort_t* ad_ = lds_a + (buf) * 8192 + tid * 8;                        \
        gload_lds16(as_,          ad_);                                        \
        gload_lds16(as_ + 16384,  ad_ + 2048);                                 \
        gload_lds16(as_ + 32768,  ad_ + 4096);                                 \
        gload_lds16(as_ + 49152,  ad_ + 6144);                                 \
    }

    // ---- one tap u of the 18-tap quarter (q2 = u/9, t = u%9) ----
    #define TAPP(q2, t, qb, qn)                                                \
    {                                                                          \
        constexpr int u_ = (q2) * 9 + (t);     /* 0..17 */                     \
        constexpr int P_ = u_ & 1;                                             \
        constexpr int Q_ = P_ ^ 1;                                             \
        {   /* issue A(u+2) */                                                 \
            constexpr int lt2_ = u_ + 2;                                       \
            constexpr int tp_  = (lt2_ < 18) ? (lt2_ % 9) : (lt2_ - 18);       \
            const int cg_ = (lt2_ < 18) ? ((qb) + lt2_ / 9) : (qn);            \
            ISSUE_A(tp_, cg_, lt2_ % 3);                                       \
        }                                                                      \
        WAITVM4;                       /* own A(u+1) landed */                 \
        __builtin_amdgcn_sched_barrier(0);                                     \
        __builtin_amdgcn_s_barrier();  /* all waves' A(u+1) visible */         \
        {   /* prefetch af(u+1) -> set Q */                                    \
            const ushort_t* ar_ = lds_a + ((u_ + 1) % 3) * 8192 + abase;       \
            _Pragma("unroll")                                                  \
            for (int mi_ = 0; mi_ < 8; ++mi_)                                  \
                afr[Q_][mi_] = *(const short8*)(ar_ + mi_ * 512);              \
        }                                                                      \
        if constexpr (u_ < 17) {       /* prefetch bf(u+1) -> set Q */         \
            constexpr int u1_ = u_ + 1;                                        \
            constexpr int t1_ = u1_ % 9;                                       \
            constexpr int c1_ = u1_ / 9;                                       \
            constexpr int ky_ = t1_ / 3, kx_ = t1_ % 3;                        \
            _Pragma("unroll")                                                  \
            for (int ni_ = 0; ni_ < 8; ++ni_)                                  \
                bfr[Q_][ni_] = *(const short8*)(lds_x + bx[c1_][kx_]           \
                    + (((ni_ >> 2) + ky_) * 66) * 64 + (ni_ & 3) * 1024);      \
        }                                                                      \
        __builtin_amdgcn_s_setprio(1);                                         \
        _Pragma("unroll")                                                      \
        for (int mi_ = 0; mi_ < 8; ++mi_)                                      \
            _Pragma("unroll")                                                  \
            for (int ni_ = 0; ni_ < 8; ++ni_)                                  \
                acc[mi_][ni_] = __builtin_amdgcn_mfma_f32_16x16x32_bf16(       \
                    bfr[P_][ni_], afr[P_][mi_], acc[mi_][ni_], 0, 0, 0);       \
        __builtin_amdgcn_s_setprio(0);                                         \
        __builtin_amdgcn_sched_barrier(0);                                     \
    }

    // ---- prologue: x quarter 0; A(0)->buf0, A(1)->buf1; frags(0)->set0 ----
    STAGE_X(0);
    ISSUE_A(0, 0, 0);
    ISSUE_A(1, 0, 1);
    WAITVM0;
    asm volatile("s_waitcnt lgkmcnt(0)" ::: "memory");   // halo writes done
    __builtin_amdgcn_sched_barrier(0);
    __builtin_amdgcn_s_barrier();                        // x + A visible
    {
        const ushort_t* ar = lds_a + abase;
        #pragma unroll
        for (int mi = 0; mi < 8; ++mi) afr[0][mi] = *(const short8*)(ar + mi * 512);
        #pragma unroll
        for (int ni = 0; ni < 8; ++ni)
            bfr[0][ni] = *(const short8*)(lds_x + bx[0][0]
                          + ((ni >> 2) * 66) * 64 + (ni & 3) * 1024);
    }

    #pragma unroll 1
    for (int qt = 0; qt < 4; ++qt) {
        if (qt) {
            // quarter boundary: restage x (af of first tap already in set 0)
            __builtin_amdgcn_s_barrier();            // all waves done with x
            STAGE_X(qt);
            WAITVM0;                                 // own x + pending A landed
            __builtin_amdgcn_sched_barrier(0);
            __builtin_amdgcn_s_barrier();            // visible to all waves
            // bf(first tap of quarter) -> set 0
            #pragma unroll
            for (int ni = 0; ni < 8; ++ni)
                bfr[0][ni] = *(const short8*)(lds_x + bx[0][0]
                              + ((ni >> 2) * 66) * 64 + (ni & 3) * 1024);
        }
        const int qb = qt * 2;                       // this quarter's cg base
        const int qn = ((qt + 1) & 3) * 2;           // next quarter's cg base

        TAPP(0,0,qb,qn) TAPP(0,1,qb,qn) TAPP(0,2,qb,qn)
        TAPP(0,3,qb,qn) TAPP(0,4,qb,qn) TAPP(0,5,qb,qn)
        TAPP(0,6,qb,qn) TAPP(0,7,qb,qn) TAPP(0,8,qb,qn)
        TAPP(1,0,qb,qn) TAPP(1,1,qb,qn) TAPP(1,2,qb,qn)
        TAPP(1,3,qb,qn) TAPP(1,4,qb,qn) TAPP(1,5,qb,qn)
        TAPP(1,6,qb,qn) TAPP(1,7,qb,qn) TAPP(1,8,qb,qn)
    }
    #undef TAPP
    #undef ISSUE_A
    #undef STAGE_X

    // drain outstanding dummy A loads before epilogue
    asm volatile("s_waitcnt vmcnt(0) lgkmcnt(0)" ::: "memory");
    __builtin_amdgcn_sched_barrier(0);

    // ---- epilogue: D col = co = l15, rows = sp -> f32x4 stores ----
    #pragma unroll
    for (int mi = 0; mi < 8; ++mi) {
        const int co = wm * 128 + mi * 16 + l15;
        float* ob = out + ((size_t)(b * COUT + co)) * NSP
                  + ntile * 256 + wn * 128 + lg * 4;
        #pragma unroll
        for (int ni = 0; ni < 8; ++ni)
            *(f32x4*)(ob + (ni >> 2) * 64 + (ni & 3) * 16) = acc[mi][ni];
    }
}

// ---------------------------------------------------------------------------
// Fallback fp32 direct conv if workspace is too small.
// ---------------------------------------------------------------------------
__global__ __launch_bounds__(256)
void modconv_kernel(const float* __restrict__ x,
                    const float* __restrict__ cw,
                    const float* __restrict__ s,
                    const float* __restrict__ scale_p,
                    float* __restrict__ out) {
    const int tile = blockIdx.x;
    const int co   = blockIdx.y;
    const int b    = blockIdx.z;
    const int tid  = threadIdx.x;
    const float scale = scale_p[0];

    __shared__ float s_wt[CIN * KW];
    __shared__ float s_x[18 * 66];
    __shared__ float red[4];

    const float* cwb = cw + (size_t)co * CIN * KW;
    const float* sb  = s + b * CIN;
    float sumsq = 0.f;
    for (int i = tid; i < CIN * KW; i += 256) {
        float v = cwb[i] * scale * sb[i / KW];
        s_wt[i] = v;
        sumsq += v * v;
    }
    #pragma unroll
    for (int off = 32; off > 0; off >>= 1) sumsq += __shfl_down(sumsq, off);
    if ((tid & 63) == 0) red[tid >> 6] = sumsq;
    __syncthreads();
    const float demod = rsqrtf(red[0] + red[1] + red[2] + red[3] + 1e-8f);
    for (int i = tid; i < CIN * KW; i += 256) s_wt[i] *= demod;

    const int tx = tid & 63;
    const int tr = tid >> 6;
    const int y0 = tile * 16;
    float acc[4] = {0.f, 0.f, 0.f, 0.f};

    for (int ci = 0; ci < CIN; ++ci) {
        __syncthreads();
        const float* xb = x + ((size_t)(b * CIN + ci)) * (HH * WWS);
        for (int idx = tid; idx < 18 * 66; idx += 256) {
            const int r = idx / 66, c = idx % 66;
            const int yg = y0 - 1 + r, xg = c - 1;
            float v = 0.f;
            if (yg >= 0 && yg < HH && xg >= 0 && xg < WWS) v = xb[yg * WWS + xg];
            s_x[idx] = v;
        }
        __syncthreads();
        const float* wr = s_wt + ci * KW;
        const float w0 = wr[0], w1 = wr[1], w2 = wr[2];
        const float w3 = wr[3], w4 = wr[4], w5 = wr[5];
        const float w6 = wr[6], w7 = wr[7], w8 = wr[8];
        const int rbase = tr * 4;
        float xv[6][3];
        #pragma unroll
        for (int j = 0; j < 6; ++j)
            #pragma unroll
            for (int k = 0; k < 3; ++k) xv[j][k] = s_x[(rbase + j) * 66 + tx + k];
        #pragma unroll
        for (int i = 0; i < 4; ++i)
            acc[i] += w0 * xv[i][0] + w1 * xv[i][1] + w2 * xv[i][2]
                    + w3 * xv[i+1][0] + w4 * xv[i+1][1] + w5 * xv[i+1][2]
                    + w6 * xv[i+2][0] + w7 * xv[i+2][1] + w8 * xv[i+2][2];
    }
    float* ob = out + (((size_t)(b * COUT + co)) * HH + y0) * WWS + tx;
    #pragma unroll
    for (int i = 0; i < 4; ++i) ob[(tr * 4 + i) * WWS] = acc[i];
}

// ---------------------------------------------------------------------------
extern "C" void kernel_launch(void* const* d_in, const int* in_sizes, int n_in,
                              void* d_out, int out_size, void* d_ws, size_t ws_size,
                              hipStream_t stream) {
    const float* x       = (const float*)d_in[0];
    const float* w       = (const float*)d_in[1];
    const float* cw      = (const float*)d_in[2];
    const float* style_w = (const float*)d_in[3];
    const float* style_b = (const float*)d_in[4];
    const float* scale_p = (const float*)d_in[5];
    float*       out     = (float*)d_out;

    float*    s    = (float*)d_ws;
    ushort_t* wswt = (ushort_t*)((char*)d_ws + WT_OFF);
    ushort_t* wsx  = (ushort_t*)((char*)d_ws + X_OFF);
    float*    zp   = (float*)((char*)d_ws + ZP_OFF);

    style_kernel<<<dim3(BB), 256, 0, stream>>>(w, style_w, style_b, s);

    if (ws_size >= WS_NEEDED) {
        wt_kernel<<<dim3(COUT, BB), 256, 0, stream>>>(cw, s, scale_p, wswt, zp);
        xpose_kernel<<<dim3(64, 4, BB), 256, 0, stream>>>(x, wsx);
        conv_mfma_kernel<<<dim3(256), 256, 0, stream>>>(wswt, wsx,
                                                        (const ushort_t*)zp, out);
    } else {
        modconv_kernel<<<dim3(4, COUT, BB), 256, 0, stream>>>(x, cw, s, scale_p, out);
    }
}